// Round 1
// 411.538 us; speedup vs baseline: 1.0854x; 1.0854x over previous
//
#include <hip/hip_runtime.h>
#include <hip/hip_fp16.h>
#include <stdint.h>

// Shapes (fixed by the reference):
//   tract a: x (8192, 4096), W/M (1024, 4096), 64 conns/row
//   tract b: x (8192, 4096), W/M ( 512, 4096), 64 conns/row
//   tract c: x (8192, 2048), W/M ( 512, 2048), 32 conns/row
//   out (8192, 2048) = concat(a:1024, b:512, c:512)

#define BS_TOTAL 8192
#define SRC_A 4096
#define SRC_B 4096
#define SRC_C 2048
#define DST_A 1024
#define DST_B 512
#define DST_C 512
#define K_A 64
#define K_B 64
#define K_C 32
#define OUT_DIM 2048

// LDS layout (tract kernel): per src index one 8-byte "pair":
//   word0 = half2{row0, row1}, word1 = half2{row2, row3}
// pair index: a -> [0,4096), b -> [4096,8192), c -> [8192,10240)
#define PAIR_XB_OFF 4096
#define PAIR_XC_OFF 8192
#define PAIR_TOT 10240
#define LDS_BYTES (PAIR_TOT * 8)   // 81920 B -> 2 blocks/CU

typedef float f32x4 __attribute__((ext_vector_type(4)));

// Packed table entry: (lds_pair_idx << 16) | fp16_bits(w). idx <= 10239 fits.
// Table layout: [K/4][DST][4] uint32  == [K/4][DST] uint4, so the main kernel
// loads 4 k-entries per dst with ONE coalesced global_load_dwordx4.

// ---------------------------------------------------------------------------
// Kernel 1: one block per dst row. Collect nonzero (idx, w), counting-sort by
// LDS *bank-pair* (idx & 15, since each src idx now owns 8 B = 2 banks), then
// rotate the k-sequence per dst so the 64 lanes of a wave spread across the 16
// bank-pairs at every k step (4 lanes/pair = the b64 minimum).
// ---------------------------------------------------------------------------
__global__ __launch_bounds__(256) void compress_kernel(
    const float* __restrict__ w_a, const float* __restrict__ m_a,
    const float* __restrict__ w_b, const float* __restrict__ m_b,
    const float* __restrict__ w_c, const float* __restrict__ m_c,
    unsigned* __restrict__ pa, unsigned* __restrict__ pb,
    unsigned* __restrict__ pc) {
    __shared__ int s_cnt;
    __shared__ int s_idx[64];
    __shared__ float s_w[64];
    __shared__ int s_bankcnt[16];
    __shared__ int s_bankoff[16];
    __shared__ unsigned s_sorted[64];

    const int blk = blockIdx.x;
    const int t = threadIdx.x;

    const float *w, *m;
    unsigned* p;
    int dst, src_n, K, DST, pair_off;
    if (blk < DST_A) {
        w = w_a; m = m_a; p = pa; dst = blk;
        src_n = SRC_A; K = K_A; DST = DST_A; pair_off = 0;
    } else if (blk < DST_A + DST_B) {
        w = w_b; m = m_b; p = pb; dst = blk - DST_A;
        src_n = SRC_B; K = K_B; DST = DST_B; pair_off = PAIR_XB_OFF;
    } else {
        w = w_c; m = m_c; p = pc; dst = blk - DST_A - DST_B;
        src_n = SRC_C; K = K_C; DST = DST_C; pair_off = PAIR_XC_OFF;
    }

    if (t == 0) s_cnt = 0;
    if (t < 16) s_bankcnt[t] = 0;
    __syncthreads();

    const float* mrow = m + (size_t)dst * src_n;
    const float* wrow = w + (size_t)dst * src_n;
    const int per_thread = src_n >> 8;   // 16 or 8
    for (int i = 0; i < per_thread; ++i) {
        int e = t + (i << 8);
        float mv = mrow[e];
        if (mv != 0.0f) {
            int pos = atomicAdd(&s_cnt, 1);
            if (pos < 64) {
                s_idx[pos] = e;
                s_w[pos] = wrow[e] * mv;
            }
        }
    }
    __syncthreads();
    int cnt = s_cnt;
    if (cnt > K) cnt = K;

    // histogram by bank-pair
    if (t < cnt) atomicAdd(&s_bankcnt[s_idx[t] & 15], 1);
    __syncthreads();
    if (t == 0) {
        int acc = 0;
        for (int b = 0; b < 16; ++b) {
            s_bankoff[b] = acc;
            acc += s_bankcnt[b];
        }
    }
    __syncthreads();
    // scatter sorted-by-bank-pair, already packed
    if (t < cnt) {
        int idx = s_idx[t];
        int j = atomicAdd(&s_bankoff[idx & 15], 1);
        unsigned hb = (unsigned)__half_as_ushort(__float2half(s_w[t]));
        s_sorted[j] = ((unsigned)(pair_off + idx) << 16) | hb;
    }
    __syncthreads();
    // pad (defensive; masks have exactly K nonzeros). w=0 -> contributes 0.
    if (t >= cnt && t < K) s_sorted[t] = ((unsigned)pair_off << 16);
    __syncthreads();

    // rotate and store into [K/4][DST][4] layout:
    //   slot t of dst holds sorted[(t + rot) % K]; sum order is irrelevant,
    //   only the per-step bank spread matters.
    if (t < K) {
        int rot = (K == 64) ? ((dst & 15) << 2) : ((dst & 15) << 1);
        unsigned v = s_sorted[(t + rot) % K];
        p[(((t >> 2) * DST) + dst) * 4 + (t & 3)] = v;
    }
}

// ---------------------------------------------------------------------------
// Kernel 2: one block per FOUR (b,s) rows. Stage 4 rows as fp16 pairs in LDS
// (8 B per src idx), then each thread computes 8 dst columns for all 4 rows.
// Table entries amortized 4x; table loaded as uint4 (4 k per VMEM op);
// gather is one ds_read_b64 per entry feeding 4 FMAs (v_fma_mix candidates).
// ---------------------------------------------------------------------------
__global__ __launch_bounds__(256, 2) void tract_kernel(
    const float* __restrict__ x_a, const float* __restrict__ x_b,
    const float* __restrict__ x_c,
    const unsigned* __restrict__ pa, const unsigned* __restrict__ pb,
    const unsigned* __restrict__ pc,
    float* __restrict__ out) {
    extern __shared__ unsigned xs[];
    const int t = threadIdx.x;
    const size_t r0 = (size_t)blockIdx.x * 4;

    // ---- staging: 2560 quads (4 src each), 10 per thread, coalesced ----
    const f32x4* a0 = (const f32x4*)(x_a + (r0 + 0) * SRC_A);
    const f32x4* a1 = (const f32x4*)(x_a + (r0 + 1) * SRC_A);
    const f32x4* a2 = (const f32x4*)(x_a + (r0 + 2) * SRC_A);
    const f32x4* a3 = (const f32x4*)(x_a + (r0 + 3) * SRC_A);
    const f32x4* b0 = (const f32x4*)(x_b + (r0 + 0) * SRC_B);
    const f32x4* b1 = (const f32x4*)(x_b + (r0 + 1) * SRC_B);
    const f32x4* b2 = (const f32x4*)(x_b + (r0 + 2) * SRC_B);
    const f32x4* b3 = (const f32x4*)(x_b + (r0 + 3) * SRC_B);
    const f32x4* c0 = (const f32x4*)(x_c + (r0 + 0) * SRC_C);
    const f32x4* c1 = (const f32x4*)(x_c + (r0 + 1) * SRC_C);
    const f32x4* c2 = (const f32x4*)(x_c + (r0 + 2) * SRC_C);
    const f32x4* c3 = (const f32x4*)(x_c + (r0 + 3) * SRC_C);
    uint4* xs4 = (uint4*)xs;

#pragma unroll
    for (int i = 0; i < 10; ++i) {
        int q = t + (i << 8);                 // quad index, 0..2559
        const f32x4 *s0, *s1, *s2, *s3;
        int qo;
        if (q < 1024)      { s0 = a0; s1 = a1; s2 = a2; s3 = a3; qo = q; }
        else if (q < 2048) { s0 = b0; s1 = b1; s2 = b2; s3 = b3; qo = q - 1024; }
        else               { s0 = c0; s1 = c1; s2 = c2; s3 = c3; qo = q - 2048; }
        f32x4 v0 = s0[qo];
        f32x4 v1 = s1[qo];
        f32x4 v2 = s2[qo];
        f32x4 v3 = s3[qo];
        // pair(i) = { h2(r0,r1), h2(r2,r3) }; quad covers pairs 4q..4q+3
        uint4 w0, w1;
        __half2 h;
        h = __floats2half2_rn(v0.x, v1.x); w0.x = *(unsigned*)&h;
        h = __floats2half2_rn(v2.x, v3.x); w0.y = *(unsigned*)&h;
        h = __floats2half2_rn(v0.y, v1.y); w0.z = *(unsigned*)&h;
        h = __floats2half2_rn(v2.y, v3.y); w0.w = *(unsigned*)&h;
        h = __floats2half2_rn(v0.z, v1.z); w1.x = *(unsigned*)&h;
        h = __floats2half2_rn(v2.z, v3.z); w1.y = *(unsigned*)&h;
        h = __floats2half2_rn(v0.w, v1.w); w1.z = *(unsigned*)&h;
        h = __floats2half2_rn(v2.w, v3.w); w1.w = *(unsigned*)&h;
        xs4[2 * q]     = w0;
        xs4[2 * q + 1] = w1;
    }
    __syncthreads();

    const uint2* xp = (const uint2*)xs;
    float* o0 = out + (r0 + 0) * OUT_DIM;
    float* o1 = out + (r0 + 1) * OUT_DIM;
    float* o2 = out + (r0 + 2) * OUT_DIM;
    float* o3 = out + (r0 + 3) * OUT_DIM;

// one entry -> 4 MACs (rows 0..3). fmaf(w, cvt(f16), acc) -> v_fma_mix_f32.
#define PROC(u) {                                                            \
        uint2 xv = xp[(u) >> 16];                                            \
        float w = __half2float(__ushort_as_half((unsigned short)((u) & 0xffffu))); \
        const __half2 hlo = *(const __half2*)&xv.x;                          \
        const __half2 hhi = *(const __half2*)&xv.y;                          \
        acc0 = fmaf(w, __low2float(hlo), acc0);                              \
        acc1 = fmaf(w, __high2float(hlo), acc1);                             \
        acc2 = fmaf(w, __low2float(hhi), acc2);                              \
        acc3 = fmaf(w, __high2float(hhi), acc3); }

    const uint4* ta = (const uint4*)pa;
    const uint4* tb = (const uint4*)pb;
    const uint4* tc = (const uint4*)pc;

    // tract a: dst = t + o*256, o = 0..3
#pragma unroll 1
    for (int o = 0; o < 4; ++o) {
        int dst = t + (o << 8);
        float acc0 = 0.0f, acc1 = 0.0f, acc2 = 0.0f, acc3 = 0.0f;
#pragma unroll
        for (int k4 = 0; k4 < (K_A >> 2); ++k4) {
            uint4 e = ta[k4 * DST_A + dst];
            PROC(e.x) PROC(e.y) PROC(e.z) PROC(e.w)
        }
        __builtin_nontemporal_store(acc0, o0 + dst);
        __builtin_nontemporal_store(acc1, o1 + dst);
        __builtin_nontemporal_store(acc2, o2 + dst);
        __builtin_nontemporal_store(acc3, o3 + dst);
    }
    // tract b
#pragma unroll 1
    for (int o = 0; o < 2; ++o) {
        int dst = t + (o << 8);
        float acc0 = 0.0f, acc1 = 0.0f, acc2 = 0.0f, acc3 = 0.0f;
#pragma unroll
        for (int k4 = 0; k4 < (K_B >> 2); ++k4) {
            uint4 e = tb[k4 * DST_B + dst];
            PROC(e.x) PROC(e.y) PROC(e.z) PROC(e.w)
        }
        __builtin_nontemporal_store(acc0, o0 + DST_A + dst);
        __builtin_nontemporal_store(acc1, o1 + DST_A + dst);
        __builtin_nontemporal_store(acc2, o2 + DST_A + dst);
        __builtin_nontemporal_store(acc3, o3 + DST_A + dst);
    }
    // tract c
#pragma unroll 1
    for (int o = 0; o < 2; ++o) {
        int dst = t + (o << 8);
        float acc0 = 0.0f, acc1 = 0.0f, acc2 = 0.0f, acc3 = 0.0f;
#pragma unroll
        for (int k4 = 0; k4 < (K_C >> 2); ++k4) {
            uint4 e = tc[k4 * DST_C + dst];
            PROC(e.x) PROC(e.y) PROC(e.z) PROC(e.w)
        }
        __builtin_nontemporal_store(acc0, o0 + DST_A + DST_B + dst);
        __builtin_nontemporal_store(acc1, o1 + DST_A + DST_B + dst);
        __builtin_nontemporal_store(acc2, o2 + DST_A + DST_B + dst);
        __builtin_nontemporal_store(acc3, o3 + DST_A + DST_B + dst);
    }
#undef PROC
}

// ---------------------------------------------------------------------------
extern "C" void kernel_launch(void* const* d_in, const int* in_sizes, int n_in,
                              void* d_out, int out_size, void* d_ws, size_t ws_size,
                              hipStream_t stream) {
    // setup_inputs() dict order: x_a, w_a, m_a, x_b, w_b, m_b, x_c, w_c, m_c
    const float* x_a = (const float*)d_in[0];
    const float* w_a = (const float*)d_in[1];
    const float* m_a = (const float*)d_in[2];
    const float* x_b = (const float*)d_in[3];
    const float* w_b = (const float*)d_in[4];
    const float* m_b = (const float*)d_in[5];
    const float* x_c = (const float*)d_in[6];
    const float* w_c = (const float*)d_in[7];
    const float* m_c = (const float*)d_in[8];
    float* out = (float*)d_out;

    // Workspace: packed tables (uint32 = idx<<16 | fp16 w), [K/4][DST][4].
    //   pa: 64*1024*4 = 262144 B, pb: 64*512*4 = 131072 B, pc: 32*512*4 = 65536 B
    char* ws = (char*)d_ws;
    unsigned* pa = (unsigned*)(ws);
    unsigned* pb = (unsigned*)(ws + 262144);
    unsigned* pc = (unsigned*)(ws + 262144 + 131072);

    static bool configured = false;
    if (!configured) {
        hipFuncSetAttribute(reinterpret_cast<const void*>(&tract_kernel),
                            hipFuncAttributeMaxDynamicSharedMemorySize, LDS_BYTES);
        configured = true;
    }

    compress_kernel<<<DST_A + DST_B + DST_C, 256, 0, stream>>>(
        w_a, m_a, w_b, m_b, w_c, m_c, pa, pb, pc);
    tract_kernel<<<BS_TOTAL / 4, 256, LDS_BYTES, stream>>>(x_a, x_b, x_c, pa, pb, pc, out);
}

// Round 2
// 380.931 us; speedup vs baseline: 1.1726x; 1.0803x over previous
//
#include <hip/hip_runtime.h>
#include <hip/hip_fp16.h>
#include <stdint.h>

// Shapes (fixed by the reference):
//   tract a: x (8192, 4096), W/M (1024, 4096), 64 conns/row
//   tract b: x (8192, 4096), W/M ( 512, 4096), 64 conns/row
//   tract c: x (8192, 2048), W/M ( 512, 2048), 32 conns/row
//   out (8192, 2048) = concat(a:1024, b:512, c:512)
//
// Round-2 structure: per-TRACT blocks (tracts share nothing, so fusing them
// into one block only bloated LDS). 4 rows/block, 32 KB LDS -> 5 blocks/CU
// (20 waves, ~62% occupancy) vs round-1's 80 KB -> 2 blocks/CU (22%).

#define BS_TOTAL 8192
#define SRC_A 4096
#define SRC_B 4096
#define SRC_C 2048
#define DST_A 1024
#define DST_B 512
#define DST_C 512
#define K_A 64
#define K_B 64
#define K_C 32
#define OUT_DIM 2048
#define ROWS 4

#define NBLK_A (BS_TOTAL / ROWS)              // 2048
#define NBLK_B (BS_TOTAL / ROWS)              // 2048
#define NBLK_C (BS_TOTAL / ROWS)              // 2048
#define LDS_BYTES (SRC_A * 8)                 // 32 KB (A/B full; C uses half)

typedef float f32x4 __attribute__((ext_vector_type(4)));

// LDS layout (tract kernel): per src index one 8-byte "pair":
//   word0 = half2{row0, row1}, word1 = half2{row2, row3}
// Table entry: (local_src_idx << 16) | fp16_bits(w). Table layout
// [K/4][DST][4] uint32 == [K/4][DST] uint4 -> one coalesced dwordx4 per dst
// fetches 4 k-entries.

// ---------------------------------------------------------------------------
// Kernel 1: one block per dst row. Scan the mask (float4), collect nonzero
// indices, counting-sort by LDS bank-pair (idx & 15: each src owns 8 B = 2
// banks), rotate the k-sequence per dst so a wave's 64 lanes spread across
// the 16 bank-pairs at every k step (4 lanes/pair = the b64 minimum).
// ---------------------------------------------------------------------------
__global__ __launch_bounds__(256) void compress_kernel(
    const float* __restrict__ w_a, const float* __restrict__ m_a,
    const float* __restrict__ w_b, const float* __restrict__ m_b,
    const float* __restrict__ w_c, const float* __restrict__ m_c,
    unsigned* __restrict__ pa, unsigned* __restrict__ pb,
    unsigned* __restrict__ pc) {
    __shared__ int s_cnt;
    __shared__ int s_idx[64];
    __shared__ int s_bankcnt[16];
    __shared__ int s_bankoff[16];
    __shared__ unsigned s_sorted[64];

    const int blk = blockIdx.x;
    const int t = threadIdx.x;

    const float *w, *m;
    unsigned* p;
    int dst, src_n, K, DST;
    if (blk < DST_A) {
        w = w_a; m = m_a; p = pa; dst = blk;
        src_n = SRC_A; K = K_A; DST = DST_A;
    } else if (blk < DST_A + DST_B) {
        w = w_b; m = m_b; p = pb; dst = blk - DST_A;
        src_n = SRC_B; K = K_B; DST = DST_B;
    } else {
        w = w_c; m = m_c; p = pc; dst = blk - DST_A - DST_B;
        src_n = SRC_C; K = K_C; DST = DST_C;
    }

    if (t == 0) s_cnt = 0;
    if (t < 16) s_bankcnt[t] = 0;
    __syncthreads();

    const float* mrow = m + (size_t)dst * src_n;
    const float* wrow = w + (size_t)dst * src_n;
    const f32x4* m4 = (const f32x4*)mrow;
    const int nq = src_n >> 10;              // float4s per thread: 4 or 2
    for (int i = 0; i < nq; ++i) {
        int q = t + (i << 8);
        f32x4 mv = m4[q];
#pragma unroll
        for (int j = 0; j < 4; ++j) {
            if (mv[j] != 0.0f) {
                int pos = atomicAdd(&s_cnt, 1);
                if (pos < 64) s_idx[pos] = 4 * q + j;
            }
        }
    }
    __syncthreads();
    int cnt = s_cnt;
    if (cnt > K) cnt = K;

    // histogram by bank-pair
    if (t < cnt) atomicAdd(&s_bankcnt[s_idx[t] & 15], 1);
    __syncthreads();
    if (t == 0) {
        int acc = 0;
        for (int b = 0; b < 16; ++b) {
            s_bankoff[b] = acc;
            acc += s_bankcnt[b];
        }
    }
    __syncthreads();
    // scatter sorted-by-bank-pair, packed (scattered w/m gather: 64 lanes)
    if (t < cnt) {
        int idx = s_idx[t];
        int j = atomicAdd(&s_bankoff[idx & 15], 1);
        float wv = wrow[idx] * mrow[idx];
        unsigned hb = (unsigned)__half_as_ushort(__float2half(wv));
        s_sorted[j] = ((unsigned)idx << 16) | hb;
    }
    __syncthreads();
    // pad (defensive; masks have exactly K nonzeros). idx=0,w=0 -> adds 0.
    if (t >= cnt && t < K) s_sorted[t] = 0u;
    __syncthreads();

    // rotate and store into [K/4][DST][4]; sum order is irrelevant, only the
    // per-k-step bank spread across a wave's 64 consecutive dst matters.
    if (t < K) {
        int rot = (K == 64) ? ((dst & 15) << 2) : ((dst & 15) << 1);
        unsigned v = s_sorted[(t + rot) & (K - 1)];
        p[(((t >> 2) * DST) + dst) * 4 + (t & 3)] = v;
    }
}

// ---------------------------------------------------------------------------
// Kernel 2: per-tract blocks, 4 rows each. Stage 4 rows as fp16 pairs in LDS
// (8 B per src idx), then each thread computes NOUT dst columns for all 4
// rows: table uint4 load (4 k-entries) -> 4x { ds_read_b64 + 4 v_fma_mix }.
// ---------------------------------------------------------------------------

// one entry -> 4 MACs (rows 0..3). fmaf(w, cvt(f16), acc) -> v_fma_mix_f32.
#define PROC(u) {                                                            \
        uint2 xv = xp[(u) >> 16];                                            \
        float w = __half2float(__ushort_as_half((unsigned short)((u) & 0xffffu))); \
        const __half2 hlo = *(const __half2*)&xv.x;                          \
        const __half2 hhi = *(const __half2*)&xv.y;                          \
        acc0 = fmaf(w, __low2float(hlo), acc0);                              \
        acc1 = fmaf(w, __high2float(hlo), acc1);                             \
        acc2 = fmaf(w, __low2float(hhi), acc2);                              \
        acc3 = fmaf(w, __high2float(hhi), acc3); }

template <int SRCN, int KQ, int DSTN, int NOUT>
__device__ __forceinline__ void do_tract(
    const float* __restrict__ xsrc, const uint4* __restrict__ tab,
    float* __restrict__ outb,   // out + r0*OUT_DIM + tract col offset
    size_t r0, int t, unsigned* xs) {
    // ---- staging: SRCN/4 quads; quad q covers srcs 4q..4q+3 of 4 rows ----
    const f32x4* s0 = (const f32x4*)(xsrc + (r0 + 0) * SRCN);
    const f32x4* s1 = (const f32x4*)(xsrc + (r0 + 1) * SRCN);
    const f32x4* s2 = (const f32x4*)(xsrc + (r0 + 2) * SRCN);
    const f32x4* s3 = (const f32x4*)(xsrc + (r0 + 3) * SRCN);
    uint4* xs4 = (uint4*)xs;

#pragma unroll
    for (int i = 0; i < (SRCN >> 10); ++i) {
        int q = t + (i << 8);
        f32x4 v0 = s0[q];
        f32x4 v1 = s1[q];
        f32x4 v2 = s2[q];
        f32x4 v3 = s3[q];
        uint4 w0, w1;
        __half2 h;
        h = __floats2half2_rn(v0.x, v1.x); w0.x = *(unsigned*)&h;
        h = __floats2half2_rn(v2.x, v3.x); w0.y = *(unsigned*)&h;
        h = __floats2half2_rn(v0.y, v1.y); w0.z = *(unsigned*)&h;
        h = __floats2half2_rn(v2.y, v3.y); w0.w = *(unsigned*)&h;
        h = __floats2half2_rn(v0.z, v1.z); w1.x = *(unsigned*)&h;
        h = __floats2half2_rn(v2.z, v3.z); w1.y = *(unsigned*)&h;
        h = __floats2half2_rn(v0.w, v1.w); w1.z = *(unsigned*)&h;
        h = __floats2half2_rn(v2.w, v3.w); w1.w = *(unsigned*)&h;
        xs4[2 * q]     = w0;
        xs4[2 * q + 1] = w1;
    }
    __syncthreads();

    const uint2* xp = (const uint2*)xs;
    float* o0 = outb;
    float* o1 = outb + OUT_DIM;
    float* o2 = outb + 2 * OUT_DIM;
    float* o3 = outb + 3 * OUT_DIM;

#pragma unroll 1
    for (int o = 0; o < NOUT; ++o) {
        int dst = t + (o << 8);
        float acc0 = 0.0f, acc1 = 0.0f, acc2 = 0.0f, acc3 = 0.0f;
#pragma unroll
        for (int k4 = 0; k4 < KQ; ++k4) {
            uint4 e = tab[k4 * DSTN + dst];
            PROC(e.x) PROC(e.y) PROC(e.z) PROC(e.w)
        }
        __builtin_nontemporal_store(acc0, o0 + dst);
        __builtin_nontemporal_store(acc1, o1 + dst);
        __builtin_nontemporal_store(acc2, o2 + dst);
        __builtin_nontemporal_store(acc3, o3 + dst);
    }
}

__global__ __launch_bounds__(256) void tract_kernel(
    const float* __restrict__ x_a, const float* __restrict__ x_b,
    const float* __restrict__ x_c,
    const unsigned* __restrict__ pa, const unsigned* __restrict__ pb,
    const unsigned* __restrict__ pc,
    float* __restrict__ out) {
    extern __shared__ unsigned xs[];
    const int t = threadIdx.x;
    const int blk = blockIdx.x;

    if (blk < NBLK_A) {
        size_t r0 = (size_t)blk * ROWS;
        do_tract<SRC_A, K_A / 4, DST_A, 4>(
            x_a, (const uint4*)pa, out + r0 * OUT_DIM, r0, t, xs);
    } else if (blk < NBLK_A + NBLK_B) {
        size_t r0 = (size_t)(blk - NBLK_A) * ROWS;
        do_tract<SRC_B, K_B / 4, DST_B, 2>(
            x_b, (const uint4*)pb, out + r0 * OUT_DIM + DST_A, r0, t, xs);
    } else {
        size_t r0 = (size_t)(blk - NBLK_A - NBLK_B) * ROWS;
        do_tract<SRC_C, K_C / 4, DST_C, 2>(
            x_c, (const uint4*)pc, out + r0 * OUT_DIM + DST_A + DST_B, r0, t, xs);
    }
}

// ---------------------------------------------------------------------------
extern "C" void kernel_launch(void* const* d_in, const int* in_sizes, int n_in,
                              void* d_out, int out_size, void* d_ws, size_t ws_size,
                              hipStream_t stream) {
    // setup_inputs() dict order: x_a, w_a, m_a, x_b, w_b, m_b, x_c, w_c, m_c
    const float* x_a = (const float*)d_in[0];
    const float* w_a = (const float*)d_in[1];
    const float* m_a = (const float*)d_in[2];
    const float* x_b = (const float*)d_in[3];
    const float* w_b = (const float*)d_in[4];
    const float* m_b = (const float*)d_in[5];
    const float* x_c = (const float*)d_in[6];
    const float* w_c = (const float*)d_in[7];
    const float* m_c = (const float*)d_in[8];
    float* out = (float*)d_out;

    // Workspace: packed tables (uint32 = idx<<16 | fp16 w), [K/4][DST][4].
    //   pa: 64*1024*4 = 262144 B, pb: 64*512*4 = 131072 B, pc: 32*512*4 = 65536 B
    char* ws = (char*)d_ws;
    unsigned* pa = (unsigned*)(ws);
    unsigned* pb = (unsigned*)(ws + 262144);
    unsigned* pc = (unsigned*)(ws + 262144 + 131072);

    compress_kernel<<<DST_A + DST_B + DST_C, 256, 0, stream>>>(
        w_a, m_a, w_b, m_b, w_c, m_c, pa, pb, pc);
    tract_kernel<<<NBLK_A + NBLK_B + NBLK_C, 256, LDS_BYTES, stream>>>(
        x_a, x_b, x_c, pa, pb, pc, out);
}